// Round 19
// baseline (198.957 us; speedup 1.0000x reference)
//
#include <hip/hip_runtime.h>
#include <math.h>

// GCN, N=50000 nodes, E=800000 edges, F_IN=128, H=128, C=16. f32 in/out; edges int32.
//
// R2: CSR-by-dst pull aggregation. R3-R6: bf16 staging, counting-sort CSR,
// vectorized gathers. R8/R9: MFMA gemm1, fragment-ordered W1. R13: gemm2 fused
// into l1. R14: packed-uint CSR. R15/R16: contiguous row gathers, single pass.
// R18: h1 staged fp8 e4m3 (halved gather payload; absmax unmoved).
// R19: l1_fused one-node-per-wave (kills E[max(deg0,deg1)] ~25% divergence
//      waste; rowptr becomes wave-uniform s_load) + skewed LDS segments for
//      the gemm2 k-split (stride 36 rows / 516 w2s -> kq groups on distinct
//      banks; 5.4M SQ_LDS_BANK_CONFLICT was 4-way on all 32 dot iterations).

#define NBUCKET_SHIFT 8                   // bucket = dst >> 8 (256 nodes/bucket)
#define BIN_CHUNK 4096                    // edges per binning block

typedef __bf16 bf16x8 __attribute__((ext_vector_type(8)));
typedef float  f32x4  __attribute__((ext_vector_type(4)));
typedef float  f32x2  __attribute__((ext_vector_type(2)));

__device__ __forceinline__ unsigned short pack_bf16(float f) {
    unsigned u = __float_as_uint(f);
    return (unsigned short)((u + 0x7fffu + ((u >> 16) & 1u)) >> 16);   // RNE
}

// accumulate one 16 B chunk (16 fp8 features) into 8 f32x2 regs
__device__ __forceinline__ void acc_fp8x16(f32x2* a, uint4 v) {
    a[0] += __builtin_amdgcn_cvt_pk_f32_fp8(v.x, false);
    a[1] += __builtin_amdgcn_cvt_pk_f32_fp8(v.x, true);
    a[2] += __builtin_amdgcn_cvt_pk_f32_fp8(v.y, false);
    a[3] += __builtin_amdgcn_cvt_pk_f32_fp8(v.y, true);
    a[4] += __builtin_amdgcn_cvt_pk_f32_fp8(v.z, false);
    a[5] += __builtin_amdgcn_cvt_pk_f32_fp8(v.z, true);
    a[6] += __builtin_amdgcn_cvt_pk_f32_fp8(v.w, false);
    a[7] += __builtin_amdgcn_cvt_pk_f32_fp8(v.w, true);
}

// ---------------- CSR phase 1 + W1 fragment pack (merged, independent data) ---
__global__ __launch_bounds__(256)
void count_wt_kernel(const int* __restrict__ dst, int* __restrict__ bktcnt,
                     int E, int nbuckets, int nbins,
                     const float* __restrict__ W, unsigned short* __restrict__ wtp) {
    const int blk = blockIdx.x;
    const int tid = threadIdx.x;
    if (blk >= nbins) {               // W1 pack: wtp[(t*4+ks)*512 + lane*8 + j]
        int idx = (blk - nbins) * 256 + tid;   // 0..16383
        int j    = idx & 7;
        int lane = (idx >> 3) & 63;
        int ks   = (idx >> 9) & 3;
        int t    = idx >> 11;
        int n = t * 16 + (lane & 15);
        int k = ks * 32 + ((lane >> 4) << 3) + j;
        wtp[idx] = pack_bf16(W[k * 128 + n]);
        return;
    }
    __shared__ int cnt[256];
    cnt[tid] = 0;
    __syncthreads();
    const int e0 = blk * BIN_CHUNK;
    const int n = min(BIN_CHUNK, E - e0);
    for (int i = tid; i < n; i += 256)
        atomicAdd(&cnt[dst[e0 + i] >> NBUCKET_SHIFT], 1);
    __syncthreads();
    if (tid < nbuckets && cnt[tid] > 0) atomicAdd(&bktcnt[tid], cnt[tid]);
}

// ---------------- phase 2: bin edges into bucket-major packed-uint array ------
__global__ __launch_bounds__(256)
void bin_kernel(const int* __restrict__ src, const int* __restrict__ dst,
                const int* __restrict__ bktcnt, int* __restrict__ bcur,
                unsigned* __restrict__ pairs, int E, int nbuckets) {
    __shared__ unsigned spair[BIN_CHUNK];   // 16 KB (packed edges)
    __shared__ int lcnt[256];
    __shared__ int lbase[256];
    __shared__ int sbase[256];
    const int tid = threadIdx.x;
    const int e0 = blockIdx.x * BIN_CHUNK;
    const int cnt = min(BIN_CHUNK, E - e0);

    int v = (tid < nbuckets) ? bktcnt[tid] : 0;
    sbase[tid] = v;
    lcnt[tid] = 0;
    __syncthreads();
#pragma unroll
    for (int off = 1; off < 256; off <<= 1) {
        int u = (tid >= off) ? sbase[tid - off] : 0;
        __syncthreads();
        sbase[tid] += u;
        __syncthreads();
    }
    int excl = sbase[tid] - v;
    __syncthreads();
    sbase[tid] = excl;
    __syncthreads();

    for (int i = tid; i < cnt; i += 256) {
        unsigned s = (unsigned)src[e0 + i], d = (unsigned)dst[e0 + i];
        spair[i] = (d >> NBUCKET_SHIFT) << 24 | (d & 255u) << 16 | s;
        atomicAdd(&lcnt[d >> NBUCKET_SHIFT], 1);
    }
    __syncthreads();

    if (tid < nbuckets) {
        int c = lcnt[tid];
        lbase[tid] = (c > 0) ? atomicAdd(&bcur[tid], c) : 0;
        lcnt[tid] = 0;   // reuse as local cursor
    }
    __syncthreads();

    for (int i = tid; i < cnt; i += 256) {
        unsigned p = spair[i];
        int b = (int)(p >> 24);
        int off = atomicAdd(&lcnt[b], 1);
        pairs[sbase[b] + lbase[b] + off] = p;
    }
}

// ---------------- phase 3: per-bucket rowptr + dinv + colsrc ------------------
__global__ __launch_bounds__(256)
void bucket_build_kernel(const int* __restrict__ bktcnt, const unsigned* __restrict__ pairs,
                         int* __restrict__ rowptr, float* __restrict__ dinv,
                         int* __restrict__ colsrc, int N, int E, int nbuckets) {
    __shared__ int cnt[256];
    __shared__ int sm[256];
    const int tid = threadIdx.x;
    const int blk = blockIdx.x;
    const int nb0 = blk << NBUCKET_SHIFT;

    int bv = (tid < nbuckets) ? bktcnt[tid] : 0;
    sm[tid] = bv;
    cnt[tid] = 0;
    __syncthreads();
#pragma unroll
    for (int off = 1; off < 256; off <<= 1) {
        int u = (tid >= off) ? sm[tid - off] : 0;
        __syncthreads();
        sm[tid] += u;
        __syncthreads();
    }
    __syncthreads();
    const int hi0 = sm[blk];
    const int lo = hi0 - bktcnt[blk];
    const int hi = hi0;
    __syncthreads();

    for (int i = lo + tid; i < hi; i += 256)
        atomicAdd(&cnt[(int)(pairs[i] >> 16) & 255], 1);
    __syncthreads();

    int v = cnt[tid];
    sm[tid] = v;
    __syncthreads();
#pragma unroll
    for (int off = 1; off < 256; off <<= 1) {
        int u = (tid >= off) ? sm[tid - off] : 0;
        __syncthreads();
        sm[tid] += u;
        __syncthreads();
    }
    int excl = sm[tid] - v;
    int node = nb0 + tid;
    if (node < N) {
        rowptr[node] = lo + excl;
        dinv[node] = rsqrtf((float)v + 1.0f);   // +1 self-loop
    }
    __syncthreads();
    cnt[tid] = lo + excl;   // reuse as scatter cursor
    __syncthreads();
    for (int i = lo + tid; i < hi; i += 256) {
        unsigned p = pairs[i];
        int pos = atomicAdd(&cnt[(int)(p >> 16) & 255], 1);
        colsrc[pos] = (int)(p & 0xffffu);
    }
    if (blk == 0 && tid == 0) rowptr[N] = E;
}

// ---------------- gemm1: MFMA bf16, hi/lo split-A, fp8 e4m3 output ------------
// h1b row-major fp8: node row = 128 B (32 uints). Slot k (8 B) = feats k*8..+7.
__global__ __launch_bounds__(256)
void gemm1_mfma_kernel(const float* __restrict__ x, const unsigned short* __restrict__ wtp,
                       const float* __restrict__ dinv, unsigned* __restrict__ h1b, int N) {
    __shared__ float lds[4][16 * 132];   // 33792 B
    const int tid = threadIdx.x, wave = tid >> 6, lane = tid & 63;
    const int q = lane >> 4, m = lane & 15;
    const int row0 = blockIdx.x * 64 + wave * 16;
    const int row = row0 + m;
    const int rowc = (row < N) ? row : (N - 1);   // clamp (OOB rows masked at store)

    f32x4 acc[8];
#pragma unroll
    for (int t = 0; t < 8; t++) acc[t] = (f32x4)0.0f;

#pragma unroll
    for (int ks = 0; ks < 4; ks++) {
        const float4* xp = (const float4*)(x + (size_t)rowc * 128 + ks * 32 + q * 8);
        float4 f0 = xp[0], f1 = xp[1];
        float fv[8] = {f0.x, f0.y, f0.z, f0.w, f1.x, f1.y, f1.z, f1.w};
        bf16x8 ah, al;
#pragma unroll
        for (int j = 0; j < 8; j++) {
            __bf16 h = (__bf16)fv[j];
            ah[j] = h;
            al[j] = (__bf16)(fv[j] - (float)h);
        }
#pragma unroll
        for (int t = 0; t < 8; t++) {
            bf16x8 b = *(const bf16x8*)(wtp + (size_t)(t * 4 + ks) * 512 + lane * 8);
            acc[t] = __builtin_amdgcn_mfma_f32_16x16x32_bf16(ah, b, acc[t], 0, 0, 0);
            acc[t] = __builtin_amdgcn_mfma_f32_16x16x32_bf16(al, b, acc[t], 0, 0, 0);
        }
    }

#pragma unroll
    for (int t = 0; t < 8; t++)
#pragma unroll
        for (int r = 0; r < 4; r++)
            lds[wave][(q * 4 + r) * 132 + t * 16 + m] = acc[t][r];
    __syncthreads();

    const int r2 = lane >> 2, j = lane & 3;
    const int orow = row0 + r2;
    if (orow < N) {
        float dv = dinv[orow];
        const float* lrow = &lds[wave][r2 * 132];
#pragma unroll
        for (int s = 0; s < 4; s++) {
            float4 a = *(const float4*)(lrow + s * 32 + j * 8);
            float4 b = *(const float4*)(lrow + s * 32 + j * 8 + 4);
            unsigned lo = __builtin_amdgcn_cvt_pk_fp8_f32(a.x * dv, a.y * dv, 0, false);
            lo = __builtin_amdgcn_cvt_pk_fp8_f32(a.z * dv, a.w * dv, lo, true);
            unsigned hi = __builtin_amdgcn_cvt_pk_fp8_f32(b.x * dv, b.y * dv, 0, false);
            hi = __builtin_amdgcn_cvt_pk_fp8_f32(b.z * dv, b.w * dv, hi, true);
            ((uint2*)h1b)[(size_t)orow * 16 + s * 4 + j] = make_uint2(lo, hi);
        }
    }
}

// ---------------- fused layer-1 pull + gemm2, one node per wave ---------------
// Lane = edge-group g (lane>>3, 0..7) x 16B chunk c (lane&7). Each edge's full
// 128-feat fp8 row = ONE contiguous 128 B gather across 8 chunk lanes; 8 edges
// per gather instruction, 16-edge main loop (2 gathers in flight per lane).
// rowptr[d] is wave-uniform -> scalar loads. Combine 8 groups via xor(8,16,32).
// gemm2: lane = k-quarter kq (lane>>4) x col (lane&15); skewed LDS segments
// (rows stride 36, w2s stride 516) put the 4 kq groups on distinct banks.
__global__ __launch_bounds__(256)
void l1_fused_kernel(const int* __restrict__ rowptr, const int* __restrict__ colsrc,
                     const float* __restrict__ dinv, const unsigned* __restrict__ h1b,
                     const float* __restrict__ b1, const float* __restrict__ W2,
                     float* __restrict__ h2s, int N) {
    __shared__ float rows[4][144];     // [wave][4 segs x 36], 2.3 KB
    __shared__ float w2s[4 * 516];     // [kq][32k x 16col (+4 pad)], 8.3 KB
    const int tid = threadIdx.x;
    const int wave = tid >> 6, lane = tid & 63;
    const int c = lane & 7;           // 16B chunk 0..7 (feats c*16..c*16+15)
    const int g = lane >> 3;          // edge group 0..7
    const int d = blockIdx.x * 4 + wave;

    // stage W2 into skewed [kq] segments: elem (k,col) -> (k>>5)*516 + (k&31)*16 + col
    for (int i = tid; i < 512; i += 256) {          // i = float4 index
        int k = i >> 2, col4 = (i & 3) * 4;
        float4 v = ((const float4*)W2)[i];
        *(float4*)&w2s[(k >> 5) * 516 + (k & 31) * 16 + col4] = v;
    }

    const uint4* hq = (const uint4*)h1b;   // node row = 8 uint4 (128 B)

    if (d < N) {
        f32x2 a[8];
#pragma unroll
        for (int j = 0; j < 8; j++) a[j] = (f32x2)0.0f;

        if (g == 0)                   // self-loop term
            acc_fp8x16(a, hq[(size_t)d * 8 + c]);

        int i = rowptr[d], end = rowptr[d + 1];   // wave-uniform
        for (; i + 16 <= end; i += 16) {  // 16 edges: 2 gathers in flight/lane
            int sA = colsrc[i + g], sB = colsrc[i + 8 + g];
            uint4 vA = hq[(size_t)sA * 8 + c];
            uint4 vB = hq[(size_t)sB * 8 + c];
            acc_fp8x16(a, vA);
            acc_fp8x16(a, vB);
        }
        for (; i + 8 <= end; i += 8) {
            int sx = colsrc[i + g];
            acc_fp8x16(a, hq[(size_t)sx * 8 + c]);
        }
        if (i < end && g < end - i)   // tail (<8 edges)
            acc_fp8x16(a, hq[(size_t)colsrc[i + g] * 8 + c]);

#pragma unroll
        for (int j = 0; j < 8; j++) { // combine the 8 edge groups
            a[j].x += __shfl_xor(a[j].x, 8, 64);
            a[j].y += __shfl_xor(a[j].y, 8, 64);
            a[j].x += __shfl_xor(a[j].x, 16, 64);
            a[j].y += __shfl_xor(a[j].y, 16, 64);
            a[j].x += __shfl_xor(a[j].x, 32, 64);
            a[j].y += __shfl_xor(a[j].y, 32, 64);
        }

        if (g == 0) {                 // relu(dinv*agg + b1) -> skewed LDS row
            float dv = dinv[d];
            // feats c*16..c*16+15 -> segment kq = c>>1, offset (c&1)*16
            float* rbase = &rows[wave][(c >> 1) * 36 + (c & 1) * 16];
#pragma unroll
            for (int t = 0; t < 4; t++) {
                float4 bb = ((const float4*)b1)[c * 4 + t];
                float4 o;
                o.x = fmaxf(a[2 * t].x * dv + bb.x, 0.0f);
                o.y = fmaxf(a[2 * t].y * dv + bb.y, 0.0f);
                o.z = fmaxf(a[2 * t + 1].x * dv + bb.z, 0.0f);
                o.w = fmaxf(a[2 * t + 1].y * dv + bb.w, 0.0f);
                *(float4*)(rbase + 4 * t) = o;
            }
        }
    }
    __syncthreads();

    // fused gemm2: lane = k-quarter kq (lane>>4) x col (lane&15)
    const int kq = lane >> 4, col = lane & 15;
    if (d < N) {
        const float* r = &rows[wave][kq * 36];
        const float* w = &w2s[kq * 516];
        float p = 0.0f;
#pragma unroll
        for (int k = 0; k < 32; k++)
            p = fmaf(r[k], w[k * 16 + col], p);
        p += __shfl_xor(p, 16, 64);   // combine k-quarters
        p += __shfl_xor(p, 32, 64);
        if (kq == 0) h2s[(size_t)d * 16 + col] = p * dinv[d];
    }
}

// ---------------- fused layer-2 pull + log_softmax ----------------
__global__ __launch_bounds__(256)
void l2_kernel(const int* __restrict__ rowptr, const int* __restrict__ colsrc,
               const float* __restrict__ dinv, const float* __restrict__ h2s,
               const float* __restrict__ b2, float* __restrict__ out, int N) {
    const int tid = threadIdx.x;
    const int wave = tid >> 6, lane = tid & 63;
    const int g = lane >> 2;          // edge group 0..15
    const int c = lane & 3;           // float4 chunk (4 feats)
    const int d = blockIdx.x * 4 + wave;
    if (d >= N) return;
    const float4* h2q = (const float4*)h2s;  // row = 4 float4

    float4 acc = make_float4(0.f, 0.f, 0.f, 0.f);
    if (g == 0) acc = h2q[d * 4 + c];        // self-loop term
    int i = rowptr[d], end = rowptr[d + 1];
    for (; i + 16 <= end; i += 16) {
        int s = colsrc[i + g];
        float4 v = h2q[s * 4 + c];
        acc.x += v.x; acc.y += v.y; acc.z += v.z; acc.w += v.w;
    }
    if (i < end && g < end - i) {            // tail (<16 edges)
        int s = colsrc[i + g];
        float4 v = h2q[s * 4 + c];
        acc.x += v.x; acc.y += v.y; acc.z += v.z; acc.w += v.w;
    }
#pragma unroll
    for (int off = 4; off <= 32; off <<= 1) {
        acc.x += __shfl_xor(acc.x, off, 64);
        acc.y += __shfl_xor(acc.y, off, 64);
        acc.z += __shfl_xor(acc.z, off, 64);
        acc.w += __shfl_xor(acc.w, off, 64);
    }
    float dv = dinv[d];
    float4 b = ((const float4*)b2)[c];
    float4 val = make_float4(acc.x * dv + b.x, acc.y * dv + b.y,
                             acc.z * dv + b.z, acc.w * dv + b.w);
    float m = fmaxf(fmaxf(val.x, val.y), fmaxf(val.z, val.w));
    m = fmaxf(m, __shfl_xor(m, 1, 64));
    m = fmaxf(m, __shfl_xor(m, 2, 64));
    float e = expf(val.x - m) + expf(val.y - m) + expf(val.z - m) + expf(val.w - m);
    e += __shfl_xor(e, 1, 64);
    e += __shfl_xor(e, 2, 64);
    float lse = m + logf(e);
    if (g == 0)
        ((float4*)out)[d * 4 + c] =
            make_float4(val.x - lse, val.y - lse, val.z - lse, val.w - lse);
}

extern "C" void kernel_launch(void* const* d_in, const int* in_sizes, int n_in,
                              void* d_out, int out_size, void* d_ws, size_t ws_size,
                              hipStream_t stream) {
    const float* x  = (const float*)d_in[0];
    const int*  ei  = (const int*)d_in[1];
    const float* W1 = (const float*)d_in[2];
    const float* b1 = (const float*)d_in[3];
    const float* W2 = (const float*)d_in[4];
    const float* b2 = (const float*)d_in[5];
    float* out = (float*)d_out;

    const int N = in_sizes[0] / 128;   // 50000 (< 65536 required for uint packing)
    const int E = in_sizes[1] / 2;     // 800000
    const int* src = ei;
    const int* dst = ei + E;
    const int nbuckets = (N + 255) >> NBUCKET_SHIFT;   // 196 (< 256 required)
    const int nbins = (E + BIN_CHUNK - 1) / BIN_CHUNK; // 196

    // Workspace layout (4B units):
    //   dinv    : N floats
    //   rowptr  : N+4 ints
    //   bktcnt  : 256 ints   \ one 2 KB memset
    //   bcur    : 256 ints   /
    //   wtp     : 128*128 bf16 (32 KB = 8192 int slots)
    //   colsrc  : E ints (3.2 MB)
    //   pairs   : E packed uints (3.2 MB)
    //   h1b     : N*32 uints (6.4 MB, row-major 128 B fp8 rows)
    //   h2s     : N*16 floats (3.2 MB)        total ~17 MB
    float*          wsf     = (float*)d_ws;
    float*          dinv    = wsf;
    int*            rowptr  = (int*)(wsf + N);
    int*            bktcnt  = rowptr + N + 4;
    int*            bcur    = bktcnt + 256;
    unsigned short* wtp     = (unsigned short*)(bcur + 256);
    int*            colsrc  = bcur + 256 + 8192;
    unsigned*       pairs   = (unsigned*)(colsrc + E);
    unsigned*       h1b     = pairs + E;
    float*          h2s     = (float*)(h1b + (size_t)N * 32);

    // ---- CSR build (count+wtpack, bin, build) ----
    hipMemsetAsync(bktcnt, 0, 512 * sizeof(int), stream);   // bktcnt + bcur
    count_wt_kernel<<<nbins + 64, 256, 0, stream>>>(dst, bktcnt, E, nbuckets,
                                                    nbins, W1, wtp);
    bin_kernel<<<nbins, 256, 0, stream>>>(src, dst, bktcnt, bcur, pairs, E, nbuckets);
    bucket_build_kernel<<<nbuckets, 256, 0, stream>>>(bktcnt, pairs, rowptr,
                                                      dinv, colsrc, N, E, nbuckets);

    // ---- layer 1 feature transform (MFMA, fp8 e4m3 out) ----
    gemm1_mfma_kernel<<<(N + 63) / 64, 256, 0, stream>>>(x, wtp, dinv, h1b, N);

    // ---- fused layer-1 pull + gemm2, one node per wave ----
    l1_fused_kernel<<<(N + 3) / 4, 256, 0, stream>>>(rowptr, colsrc, dinv, h1b,
                                                     b1, W2, h2s, N);

    // ---- fused pull-aggregation 2 + bias + log_softmax ----
    l2_kernel<<<(N + 3) / 4, 256, 0, stream>>>(rowptr, colsrc, dinv, h2s, b2, out, N);
}